// Round 3
// baseline (923.752 us; speedup 1.0000x reference)
//
#include <hip/hip_runtime.h>

#define DEVI __device__ __forceinline__

typedef short v8s __attribute__((ext_vector_type(8)));
typedef float v4f __attribute__((ext_vector_type(4)));
typedef unsigned short u16;

DEVI float bf2f(short s) {
  union { unsigned u; float f; } cv;
  cv.u = ((unsigned)(u16)s) << 16;
  return cv.f;
}
DEVI short f2bf(float f) {
  union { float f; unsigned u; } cv; cv.f = f;
  unsigned u = cv.u;
  return (short)((u + 0x7FFFu + ((u >> 16) & 1u)) >> 16);
}

// ---------------- prep: transpose + cast weights to bf16 ----------------
__global__ void prep_weights(const float* __restrict__ Wq, const float* __restrict__ Wk,
                             const float* __restrict__ Wv, const float* __restrict__ Wout,
                             short* __restrict__ WcT, short* __restrict__ WoT) {
  int n = blockIdx.x;
  int k = threadIdx.x;
  float v;
  if (n < 256)      v = Wq[k * 256 + n];
  else if (n < 512) v = Wk[k * 256 + (n - 256)];
  else              v = Wv[k * 256 + (n - 512)];
  WcT[n * 256 + k] = f2bf(v);
  if (n < 256) WoT[n * 256 + k] = f2bf(Wout[k * 256 + n]);
}

// ---------------- QKV projection GEMM: 128x128 tile, BK=64, n-fastest grid ----------------
__launch_bounds__(256, 2)
__global__ void proj_gemm(const float* __restrict__ x, const short* __restrict__ WcT,
                          const float* __restrict__ pos_emb,
                          short* __restrict__ Qb, short* __restrict__ Kb,
                          short* __restrict__ Vb) {
  __shared__ short As[128 * 64];
  __shared__ short Bs[128 * 64];
  const int t = threadIdx.x;
  const int nt = blockIdx.x;            // 0..5 (n-fastest: 6 blocks share one x row-tile)
  const int m0 = blockIdx.y * 128;
  const int n0 = nt * 128;
  const int wave = t >> 6, lane = t & 63;
  const int wm = (wave & 1) * 64, wn = (wave >> 1) * 64;
  const int lr = lane & 15, g = lane >> 4;

  v4f acc[4][4];
#pragma unroll
  for (int i = 0; i < 4; ++i)
#pragma unroll
    for (int j = 0; j < 4; ++j) acc[i][j] = (v4f){0.f, 0.f, 0.f, 0.f};

  for (int kt = 0; kt < 256; kt += 64) {
    if (kt) __syncthreads();
#pragma unroll
    for (int i = 0; i < 8; ++i) {
      int idx = t + i * 256;
      int row = idx >> 4, c4 = idx & 15;
      float4 vv = *reinterpret_cast<const float4*>(x + (size_t)(m0 + row) * 256 + kt + c4 * 4);
      short4 pk;
      pk.x = f2bf(vv.x); pk.y = f2bf(vv.y); pk.z = f2bf(vv.z); pk.w = f2bf(vv.w);
      int byte = (row * 128 + c4 * 8) ^ ((row & 7) << 4);
      *reinterpret_cast<short4*>(reinterpret_cast<char*>(As) + byte) = pk;
    }
#pragma unroll
    for (int i = 0; i < 4; ++i) {
      int idx = t + i * 256;
      int rn = idx >> 3, c = idx & 7;
      v8s vv = *reinterpret_cast<const v8s*>(WcT + (size_t)(n0 + rn) * 256 + kt + c * 8);
      int byte = (rn * 128 + c * 16) ^ ((rn & 7) << 4);
      *reinterpret_cast<v8s*>(reinterpret_cast<char*>(Bs) + byte) = vv;
    }
    __syncthreads();
#pragma unroll
    for (int kk = 0; kk < 2; ++kk) {
      v8s af[4], bfr[4];
#pragma unroll
      for (int i = 0; i < 4; ++i) {
        int row = wm + i * 16 + lr;
        int byte = (row * 128 + kk * 64 + g * 16) ^ ((row & 7) << 4);
        af[i] = *reinterpret_cast<const v8s*>(reinterpret_cast<const char*>(As) + byte);
      }
#pragma unroll
      for (int j = 0; j < 4; ++j) {
        int rn = wn + j * 16 + lr;
        int byte = (rn * 128 + kk * 64 + g * 16) ^ ((rn & 7) << 4);
        bfr[j] = *reinterpret_cast<const v8s*>(reinterpret_cast<const char*>(Bs) + byte);
      }
#pragma unroll
      for (int i = 0; i < 4; ++i)
#pragma unroll
        for (int j = 0; j < 4; ++j)
          acc[i][j] = __builtin_amdgcn_mfma_f32_16x16x32_bf16(af[i], bfr[j], acc[i][j], 0, 0, 0);
    }
  }
#pragma unroll
  for (int i = 0; i < 4; ++i) {
#pragma unroll
    for (int j = 0; j < 4; ++j) {
      int colg = n0 + wn + j * 16 + lr;
#pragma unroll
      for (int r = 0; r < 4; ++r) {
        int p = m0 + wm + i * 16 + g * 4 + r;
        float v = acc[i][j][r];
        if (nt < 2) {
          int yy = (p >> 7) & 127, xx = p & 127;
          int qi = (yy - min(max(yy, 2), 125) + 2) * 5 + (xx - min(max(xx, 2), 125) + 2);
          v += pos_emb[qi * 256 + colg];
          Qb[(size_t)p * 256 + colg] = f2bf(v);
        } else if (nt < 4) {
          Kb[(size_t)p * 256 + (colg - 256)] = f2bf(v);
        } else {
          Vb[(size_t)p * 256 + (colg - 512)] = f2bf(v);
        }
      }
    }
  }
}

// ---------------- attention: split-F online softmax, lane pair = one (pos,head) ----------------
// thread = (position, head, f-half). block = 4x4 positions * 8 heads * 2 halves = 256 threads.
__launch_bounds__(256)
__global__ void attn_kernel(const short* __restrict__ Qb, const short* __restrict__ Kb,
                            const short* __restrict__ Vb, const float* __restrict__ pos_emb,
                            short* __restrict__ ACC) {
  __shared__ float pe[25 * 256];
  for (int i = threadIdx.x; i < 1600; i += 256)
    reinterpret_cast<float4*>(pe)[i] = reinterpret_cast<const float4*>(pos_emb)[i];

  const int t = threadIdx.x;
  const int half = t & 1, h = (t >> 1) & 7, pl = t >> 4;
  const int id = blockIdx.x;
  const int b = id & 7;                 // batch -> XCD
  const int local = id >> 3;
  const int bx = local & 31, by = local >> 5;
  const int xx = bx * 4 + (pl & 3);
  const int yy = by * 4 + (pl >> 2);
  const int yc = min(max(yy, 2), 125), xc = min(max(xx, 2), 125);
  const int fo = h * 32 + half * 16;    // this thread's 16-f slice
  const size_t pbase = ((size_t)((b * 128 + yy) * 128 + xx)) * 256 + fo;
  const size_t cbase = ((size_t)((b * 128 + yc) * 128 + xc)) * 256 + fo;
  const float SCALE = 0.17677669529663689f;  // 1/sqrt(32)

  // load Q slice (before barrier; no LDS dep)
  float q[16];
  {
    v8s q0 = *reinterpret_cast<const v8s*>(Qb + pbase);
    v8s q1 = *reinterpret_cast<const v8s*>(Qb + pbase + 8);
#pragma unroll
    for (int e = 0; e < 8; ++e) { q[e] = bf2f(q0[e]); q[8 + e] = bf2f(q1[e]); }
  }
  __syncthreads();

  // qpe[s] = half-dot(q, pe[s]) * scale  (completed by the same shuffle as the QK half-dot)
  float qpe[25];
#pragma unroll
  for (int s = 0; s < 25; ++s) {
    const float* peb = pe + s * 256 + fo;
    float4 p0 = *reinterpret_cast<const float4*>(peb);
    float4 p1 = *reinterpret_cast<const float4*>(peb + 4);
    float4 p2 = *reinterpret_cast<const float4*>(peb + 8);
    float4 p3 = *reinterpret_cast<const float4*>(peb + 12);
    float d0 = q[0] * p0.x + q[1] * p0.y;
    float d1 = q[2] * p0.z + q[3] * p0.w;
    float d2 = q[4] * p1.x + q[5] * p1.y;
    float d3 = q[6] * p1.z + q[7] * p1.w;
    d0 += q[8] * p2.x + q[9] * p2.y;
    d1 += q[10] * p2.z + q[11] * p2.w;
    d2 += q[12] * p3.x + q[13] * p3.y;
    d3 += q[14] * p3.z + q[15] * p3.w;
    qpe[s] = ((d0 + d1) + (d2 + d3)) * SCALE;
  }

  float l = 0.f;
  float oa[16];
#pragma unroll
  for (int f = 0; f < 16; ++f) oa[f] = 0.f;

  const short* kb = Kb + cbase;
  const short* vb = Vb + cbase;

#pragma unroll
  for (int s = 0; s < 25; ++s) {
    const int off = ((s / 5 - 2) * 128 + (s % 5 - 2)) * 256;  // compile-time per s
    v8s k0 = *reinterpret_cast<const v8s*>(kb + off);
    v8s k1 = *reinterpret_cast<const v8s*>(kb + off + 8);
    v8s v0 = *reinterpret_cast<const v8s*>(vb + off);
    v8s v1 = *reinterpret_cast<const v8s*>(vb + off + 8);
    float d0 = 0.f, d1 = 0.f, d2 = 0.f, d3 = 0.f;
#pragma unroll
    for (int e = 0; e < 2; ++e) {
      d0 = fmaf(q[e * 4 + 0], bf2f(k0[e * 4 + 0]), d0);
      d1 = fmaf(q[e * 4 + 1], bf2f(k0[e * 4 + 1]), d1);
      d2 = fmaf(q[e * 4 + 2], bf2f(k0[e * 4 + 2]), d2);
      d3 = fmaf(q[e * 4 + 3], bf2f(k0[e * 4 + 3]), d3);
      d0 = fmaf(q[8 + e * 4 + 0], bf2f(k1[e * 4 + 0]), d0);
      d1 = fmaf(q[8 + e * 4 + 1], bf2f(k1[e * 4 + 1]), d1);
      d2 = fmaf(q[8 + e * 4 + 2], bf2f(k1[e * 4 + 2]), d2);
      d3 = fmaf(q[8 + e * 4 + 3], bf2f(k1[e * 4 + 3]), d3);
    }
    float part = fmaf((d0 + d1) + (d2 + d3), SCALE, qpe[s]);
    float full = part + __shfl_xor(part, 1);
    float w = __expf(full);
    l += w;
#pragma unroll
    for (int e = 0; e < 8; ++e) oa[e] = fmaf(w, bf2f(v0[e]), oa[e]);
#pragma unroll
    for (int e = 0; e < 8; ++e) oa[8 + e] = fmaf(w, bf2f(v1[e]), oa[8 + e]);
  }

  float inv = 1.f / l;
  v8s o0, o1;
#pragma unroll
  for (int e = 0; e < 8; ++e) { o0[e] = f2bf(oa[e] * inv); o1[e] = f2bf(oa[8 + e] * inv); }
  *reinterpret_cast<v8s*>(ACC + pbase) = o0;
  *reinterpret_cast<v8s*>(ACC + pbase + 8) = o1;
}

// ---------------- output projection GEMM: 128x128 tile, BK=64, n-fastest ----------------
__launch_bounds__(256, 2)
__global__ void out_gemm(const short* __restrict__ A, const short* __restrict__ WoT,
                         float* __restrict__ out) {
  __shared__ short As[128 * 64];
  __shared__ short Bs[128 * 64];
  const int t = threadIdx.x;
  const int nt = blockIdx.x;            // 0..1
  const int m0 = blockIdx.y * 128;
  const int n0 = nt * 128;
  const int wave = t >> 6, lane = t & 63;
  const int wm = (wave & 1) * 64, wn = (wave >> 1) * 64;
  const int lr = lane & 15, g = lane >> 4;

  v4f acc[4][4];
#pragma unroll
  for (int i = 0; i < 4; ++i)
#pragma unroll
    for (int j = 0; j < 4; ++j) acc[i][j] = (v4f){0.f, 0.f, 0.f, 0.f};

  for (int kt = 0; kt < 256; kt += 64) {
    if (kt) __syncthreads();
#pragma unroll
    for (int i = 0; i < 4; ++i) {
      int idx = t + i * 256;
      int row = idx >> 3, c = idx & 7;
      v8s vv = *reinterpret_cast<const v8s*>(A + (size_t)(m0 + row) * 256 + kt + c * 8);
      int byte = (row * 128 + c * 16) ^ ((row & 7) << 4);
      *reinterpret_cast<v8s*>(reinterpret_cast<char*>(As) + byte) = vv;
    }
#pragma unroll
    for (int i = 0; i < 4; ++i) {
      int idx = t + i * 256;
      int rn = idx >> 3, c = idx & 7;
      v8s vv = *reinterpret_cast<const v8s*>(WoT + (size_t)(n0 + rn) * 256 + kt + c * 8);
      int byte = (rn * 128 + c * 16) ^ ((rn & 7) << 4);
      *reinterpret_cast<v8s*>(reinterpret_cast<char*>(Bs) + byte) = vv;
    }
    __syncthreads();
#pragma unroll
    for (int kk = 0; kk < 2; ++kk) {
      v8s af[4], bfr[4];
#pragma unroll
      for (int i = 0; i < 4; ++i) {
        int row = wm + i * 16 + lr;
        int byte = (row * 128 + kk * 64 + g * 16) ^ ((row & 7) << 4);
        af[i] = *reinterpret_cast<const v8s*>(reinterpret_cast<const char*>(As) + byte);
      }
#pragma unroll
      for (int j = 0; j < 4; ++j) {
        int rn = wn + j * 16 + lr;
        int byte = (rn * 128 + kk * 64 + g * 16) ^ ((rn & 7) << 4);
        bfr[j] = *reinterpret_cast<const v8s*>(reinterpret_cast<const char*>(Bs) + byte);
      }
#pragma unroll
      for (int i = 0; i < 4; ++i)
#pragma unroll
        for (int j = 0; j < 4; ++j)
          acc[i][j] = __builtin_amdgcn_mfma_f32_16x16x32_bf16(af[i], bfr[j], acc[i][j], 0, 0, 0);
    }
  }
#pragma unroll
  for (int i = 0; i < 4; ++i) {
#pragma unroll
    for (int j = 0; j < 4; ++j) {
      int colg = n0 + wn + j * 16 + lr;
#pragma unroll
      for (int r = 0; r < 4; ++r) {
        int p = m0 + wm + i * 16 + g * 4 + r;
        out[(size_t)p * 256 + colg] = acc[i][j][r];
      }
    }
  }
}

extern "C" void kernel_launch(void* const* d_in, const int* in_sizes, int n_in,
                              void* d_out, int out_size, void* d_ws, size_t ws_size,
                              hipStream_t stream) {
  const float* x       = (const float*)d_in[0];
  const float* Wq      = (const float*)d_in[1];
  const float* Wk      = (const float*)d_in[2];
  const float* Wv      = (const float*)d_in[3];
  const float* Wout    = (const float*)d_in[4];
  const float* pos_emb = (const float*)d_in[5];
  float* out = (float*)d_out;

  char* ws = (char*)d_ws;
  short* WcT  = (short*)ws;                       // 768*256*2   = 393216 B
  short* WoT  = (short*)(ws + 393216);            // 256*256*2   = 131072 B
  short* Qb   = (short*)(ws + 524288);            // 131072*256*2 each
  short* Kb   = Qb + (size_t)131072 * 256;
  short* Vb   = Kb + (size_t)131072 * 256;
  short* ACCb = Vb + (size_t)131072 * 256;

  prep_weights<<<768, 256, 0, stream>>>(Wq, Wk, Wv, Wout, WcT, WoT);
  proj_gemm<<<dim3(6, 1024), 256, 0, stream>>>(x, WcT, pos_emb, Qb, Kb, Vb);
  attn_kernel<<<8192, 256, 0, stream>>>(Qb, Kb, Vb, pos_emb, ACCb);
  out_gemm<<<dim3(2, 1024), 256, 0, stream>>>(ACCb, WoT, out);
}